// Round 4
// baseline (738.683 us; speedup 1.0000x reference)
//
#include <hip/hip_runtime.h>
#include <hip/hip_bf16.h>

#define Nn 16384
#define Dd 256
#define L2E 1.4426950408889634f
#define LN2 0.6931471805599453f

typedef __attribute__((ext_vector_type(8))) int int8v;
typedef __attribute__((ext_vector_type(16))) float f32x16;

__device__ inline void gload_lds16(const void* g, void* l) {
    __builtin_amdgcn_global_load_lds(
        (const __attribute__((address_space(1))) void*)g,
        (__attribute__((address_space(3))) void*)l, 16, 0, 0);
}

// fp32 -> fp8 e4m3 (HW RNE). A pre-scaled by log2e: epilogue softplus works in
// exp2/log2 domain with no per-element muls.
__global__ __launch_bounds__(256) void cvt_kernel(
        const float4* __restrict__ a, const float4* __restrict__ b,
        int2* __restrict__ oa, int2* __restrict__ ob) {
    int i = blockIdx.x * 256 + threadIdx.x;
    float4 a0 = a[2 * i], a1 = a[2 * i + 1];
    float4 b0 = b[2 * i], b1 = b[2 * i + 1];
    int alo = __builtin_amdgcn_cvt_pk_fp8_f32(a0.x * L2E, a0.y * L2E, 0, false);
    alo     = __builtin_amdgcn_cvt_pk_fp8_f32(a0.z * L2E, a0.w * L2E, alo, true);
    int ahi = __builtin_amdgcn_cvt_pk_fp8_f32(a1.x * L2E, a1.y * L2E, 0, false);
    ahi     = __builtin_amdgcn_cvt_pk_fp8_f32(a1.z * L2E, a1.w * L2E, ahi, true);
    int blo = __builtin_amdgcn_cvt_pk_fp8_f32(b0.x, b0.y, 0, false);
    blo     = __builtin_amdgcn_cvt_pk_fp8_f32(b0.z, b0.w, blo, true);
    int bhi = __builtin_amdgcn_cvt_pk_fp8_f32(b1.x, b1.y, 0, false);
    bhi     = __builtin_amdgcn_cvt_pk_fp8_f32(b1.z, b1.w, bhi, true);
    oa[i] = make_int2(alo, ahi);
    ob[i] = make_int2(blo, bhi);
}

// 2x ds_read_b128 of one lane's 32 contiguous K-bytes, XOR-deswizzled.
__device__ inline int8v read_frag(const unsigned char* base, int rr, int cb) {
    int x = rr & 7;
    int4 lo = *(const int4*)&base[rr * 128 + (cb ^ x) * 16];
    int4 hi = *(const int4*)&base[rr * 128 + ((cb + 1) ^ x) * 16];
    int8v r;
    r[0] = lo.x; r[1] = lo.y; r[2] = lo.z; r[3] = lo.w;
    r[4] = hi.x; r[5] = hi.y; r[6] = hi.z; r[7] = hi.w;
    return r;
}

// Fused MX-fp8 GEMM (sim' = log2e * za.zb^T, unit e8m0 scales) + siglip loss.
// Tile 256x256, BK=128 bytes (2 K-tiles, both staged upfront, 128KB LDS),
// 512 thr = 8 waves (2M x 4N), wave tile 128x64 = acc[4][2] f32x16 frags of
// 32x32x64. 1 block/CU, 256-VGPR cap -> no spill (R3's killer).
__global__ __launch_bounds__(512, 2) void siglip_kernel(
        const unsigned char* __restrict__ ga,   // za*log2e fp8 [16384][256]
        const unsigned char* __restrict__ gb,   // zb fp8 [16384][256]
        const float* __restrict__ bp,           // bias scalar
        float* __restrict__ out) {
    __shared__ unsigned char As[2][256 * 128];
    __shared__ unsigned char Bs[2][256 * 128];
    __shared__ float wsum[8];

    const int tid  = threadIdx.x;
    const int lane = tid & 63;
    const int wid  = tid >> 6;
    const int wm   = wid >> 2;     // 0..1 -> 128-row slice
    const int wn   = wid & 3;      // 0..3 -> 64-col slice
    const int l31  = lane & 31;
    const int h    = lane >> 5;

    // XCD-chunked swizzle + 8x8 supertile (grid 4096 = 8 XCD x 512).
    const int bid = blockIdx.x;
    const int nid = (bid & 7) * 512 + (bid >> 3);
    const int sc  = nid >> 6, sl = nid & 63;
    const int by  = (sc >> 3) * 8 + (sl >> 3);   // 0..63
    const int bx  = (sc & 7) * 8 + (sl & 7);     // 0..63
    const size_t rowA0 = (size_t)by * 256;
    const size_t rowB0 = (size_t)bx * 256;

    const float b2 = bp[0] * L2E;

    // bias folded into MFMA C operand: acc ends as y = s' - b2
    f32x16 acc[4][2];
#pragma unroll
    for (int mf = 0; mf < 4; ++mf)
#pragma unroll
        for (int nf = 0; nf < 2; ++nf)
#pragma unroll
            for (int q = 0; q < 16; ++q) acc[mf][nf][q] = -b2;

    // LDS linear in chunk index; global SOURCE chunk pre-swizzled
    // ((c&7)^(row&7)) so read_frag's XOR'd ds_read_b128 is conflict-free.
#define STAGE(BUF, K0)                                                        \
    {                                                                         \
        _Pragma("unroll")                                                     \
        for (int p = 0; p < 4; ++p) {                                         \
            int c = p * 512 + tid; int row = c >> 3;                          \
            int scl = (c & 7) ^ (row & 7);                                    \
            gload_lds16(&ga[(rowA0 + row) * Dd + (K0) + scl * 16],            \
                        &As[BUF][c * 16]);                                    \
        }                                                                     \
        _Pragma("unroll")                                                     \
        for (int p = 0; p < 4; ++p) {                                         \
            int c = p * 512 + tid; int row = c >> 3;                          \
            int scl = (c & 7) ^ (row & 7);                                    \
            gload_lds16(&gb[(rowB0 + row) * Dd + (K0) + scl * 16],            \
                        &Bs[BUF][c * 16]);                                    \
        }                                                                     \
    }

#define COMPUTE(BUF)                                                          \
    {                                                                         \
        _Pragma("unroll")                                                     \
        for (int s = 0; s < 2; ++s) {                                         \
            int cb = s * 4 + h * 2;                                           \
            int8v aF[4], bF[2];                                               \
            _Pragma("unroll")                                                 \
            for (int mf = 0; mf < 4; ++mf)                                    \
                aF[mf] = read_frag(As[BUF], wm * 128 + mf * 32 + l31, cb);    \
            _Pragma("unroll")                                                 \
            for (int nf = 0; nf < 2; ++nf)                                    \
                bF[nf] = read_frag(Bs[BUF], wn * 64 + nf * 32 + l31, cb);     \
            _Pragma("unroll")                                                 \
            for (int mf = 0; mf < 4; ++mf)                                    \
                _Pragma("unroll")                                             \
                for (int nf = 0; nf < 2; ++nf)                                \
                    acc[mf][nf] =                                             \
                        __builtin_amdgcn_mfma_scale_f32_32x32x64_f8f6f4(      \
                            aF[mf], bF[nf], acc[mf][nf], 0, 0, 0,             \
                            0x7F7F7F7F, 0, 0x7F7F7F7F);                       \
        }                                                                     \
    }

    // ---- K = 256: both BK=128 tiles staged upfront, counted-vmcnt drains ----
    STAGE(0, 0)
    STAGE(1, 128)
    asm volatile("s_waitcnt vmcnt(8)" ::: "memory");   // tile0's 8 loads landed
    __builtin_amdgcn_s_barrier();
    COMPUTE(0)
    asm volatile("s_waitcnt vmcnt(0)" ::: "memory");   // tile1 landed
    __builtin_amdgcn_s_barrier();
    COMPUTE(1)
    // no trailing barrier: waves desync into the epilogue (VALU/trans) while
    // others finish MFMA -> cross-pipe overlap.

    // ---- epilogue ----
    // nats/elem = ln2*max(y,0) + ln(1+2^-|y|), ln(1+e) ~= e - e^2/2
    // (mean bias ~ +0.003 over N(0,23) y — far inside the 0.128 budget).
    float r1 = 0.f, r2 = 0.f, r2b = 0.f, ld = 0.f;
#pragma unroll
    for (int mf = 0; mf < 4; ++mf)
#pragma unroll
        for (int nf = 0; nf < 2; ++nf)
#pragma unroll
            for (int q = 0; q < 16; ++q) {
                float y = acc[mf][nf][q];
                r1 += fmaxf(y, 0.f);
                float e = __builtin_amdgcn_exp2f(-fabsf(y));
                r2 += e;
                r2b = fmaf(e, e, r2b);
            }

    // Diagonal correction on the 64 bx==by blocks (t=+1 there).
    if (bx == by) {
#pragma unroll
        for (int mf = 0; mf < 4; ++mf)
#pragma unroll
            for (int nf = 0; nf < 2; ++nf)
#pragma unroll
                for (int q = 0; q < 16; ++q) {
                    int i_loc = wm * 128 + mf * 32 + (q & 3) + 8 * (q >> 2) + 4 * h;
                    int j_loc = wn * 64 + nf * 32 + l31;
                    if (i_loc == j_loc) {
                        float y  = acc[mf][nf][q];
                        float u  = -(y + 2.f * b2);
                        float ey = __builtin_amdgcn_exp2f(-fabsf(y));
                        float eu = __builtin_amdgcn_exp2f(-fabsf(u));
                        float off = LN2 * fmaxf(y, 0.f) + ey - 0.5f * ey * ey;
                        float dg  = LN2 * fmaxf(u, 0.f) + eu - 0.5f * eu * eu;
                        ld += dg - off;
                    }
                }
    }

    float v = fmaf(LN2, r1, r2) - 0.5f * r2b + ld;   // nats

    // wave reduce then block reduce
#pragma unroll
    for (int off = 32; off; off >>= 1)
        v += __shfl_down(v, off);
    if (lane == 0) wsum[wid] = v;
    __syncthreads();
    if (tid == 0) {
        float t = 0.f;
#pragma unroll
        for (int w = 0; w < 8; ++w) t += wsum[w];
        atomicAdd(out, t * (1.0f / ((float)Nn * (float)Nn)));
    }
#undef STAGE
#undef COMPUTE
}

extern "C" void kernel_launch(void* const* d_in, const int* in_sizes, int n_in,
                              void* d_out, int out_size, void* d_ws, size_t ws_size,
                              hipStream_t stream) {
    const float* za   = (const float*)d_in[0];
    const float* zb   = (const float*)d_in[1];
    const float* bias = (const float*)d_in[2];

    unsigned char* wa = (unsigned char*)d_ws;
    unsigned char* wb = wa + (size_t)Nn * Dd;

    // zero the output accumulator (harness does not re-poison between replays)
    hipMemsetAsync(d_out, 0, sizeof(float), stream);

    // fp32 -> fp8 pre-pass (A pre-scaled by log2e)
    cvt_kernel<<<dim3(Nn * Dd / 2048), 256, 0, stream>>>(
        (const float4*)za, (const float4*)zb, (int2*)wa, (int2*)wb);

    // fused GEMM + loss: grid 64 x 64 = 4096 blocks
    siglip_kernel<<<dim3(4096), 512, 0, stream>>>(wa, wb, bias, (float*)d_out);
}

// Round 6
// 157.978 us; speedup vs baseline: 4.6759x; 4.6759x over previous
//
#include <hip/hip_runtime.h>
#include <hip/hip_bf16.h>

#define Nn 16384
#define Dd 256
#define L2E 1.4426950408889634f
#define LN2 0.6931471805599453f

typedef __attribute__((ext_vector_type(8))) int int8v;
typedef __attribute__((ext_vector_type(16))) float f32x16;

__device__ inline void gload_lds16(const void* g, void* l) {
    __builtin_amdgcn_global_load_lds(
        (const __attribute__((address_space(1))) void*)g,
        (__attribute__((address_space(3))) void*)l, 16, 0, 0);
}

// fp32 -> fp8 e4m3 (HW RNE). A pre-scaled by log2e: epilogue softplus works in
// exp2/log2 domain with no per-element muls.
__global__ __launch_bounds__(256) void cvt_kernel(
        const float4* __restrict__ a, const float4* __restrict__ b,
        int2* __restrict__ oa, int2* __restrict__ ob) {
    int i = blockIdx.x * 256 + threadIdx.x;
    float4 a0 = a[2 * i], a1 = a[2 * i + 1];
    float4 b0 = b[2 * i], b1 = b[2 * i + 1];
    int alo = __builtin_amdgcn_cvt_pk_fp8_f32(a0.x * L2E, a0.y * L2E, 0, false);
    alo     = __builtin_amdgcn_cvt_pk_fp8_f32(a0.z * L2E, a0.w * L2E, alo, true);
    int ahi = __builtin_amdgcn_cvt_pk_fp8_f32(a1.x * L2E, a1.y * L2E, 0, false);
    ahi     = __builtin_amdgcn_cvt_pk_fp8_f32(a1.z * L2E, a1.w * L2E, ahi, true);
    int blo = __builtin_amdgcn_cvt_pk_fp8_f32(b0.x, b0.y, 0, false);
    blo     = __builtin_amdgcn_cvt_pk_fp8_f32(b0.z, b0.w, blo, true);
    int bhi = __builtin_amdgcn_cvt_pk_fp8_f32(b1.x, b1.y, 0, false);
    bhi     = __builtin_amdgcn_cvt_pk_fp8_f32(b1.z, b1.w, bhi, true);
    oa[i] = make_int2(alo, ahi);
    ob[i] = make_int2(blo, bhi);
}

// 2x ds_read_b128 of one lane's 32 contiguous K-bytes, XOR-deswizzled.
__device__ inline int8v read_frag(const unsigned char* base, int rr, int cb) {
    int x = rr & 7;
    int4 lo = *(const int4*)&base[rr * 128 + (cb ^ x) * 16];
    int4 hi = *(const int4*)&base[rr * 128 + ((cb + 1) ^ x) * 16];
    int8v r;
    r[0] = lo.x; r[1] = lo.y; r[2] = lo.z; r[3] = lo.w;
    r[4] = hi.x; r[5] = hi.y; r[6] = hi.z; r[7] = hi.w;
    return r;
}

// Fused MX-fp8 GEMM (sim' = log2e * za.zb^T, unit e8m0 scales) + siglip loss.
// Tile 256(M)x128(N), BK=128 B, double-buffered LDS (96KB), 512 thr = 8 waves
// (4M x 2N), wave tile 64x64 -> acc[2][2] f32x16 (64 regs; ~170/256 of the
// unified file at (512,2), ~90 regs slack vs R3/R4's spill).
// NOTE: global_load_lds used ONLY with offset=0 (nonzero imm offset was R5's
// NaN — semantics unverified on gfx950; full address computed per stage).
__global__ __launch_bounds__(512, 2) void siglip_kernel(
        const unsigned char* __restrict__ ga,   // za*log2e fp8 [16384][256]
        const unsigned char* __restrict__ gb,   // zb fp8 [16384][256]
        const float* __restrict__ bp,           // bias scalar
        float* __restrict__ out) {
    __shared__ unsigned char As[2][256 * 128];
    __shared__ unsigned char Bs[2][128 * 128];
    __shared__ float wsum[8];

    const int tid  = threadIdx.x;
    const int lane = tid & 63;
    const int wid  = tid >> 6;
    const int wm   = wid >> 1;     // 0..3 -> 64-row slice of the 256-row tile
    const int wn   = wid & 1;      // 0..1 -> 64-col slice of the 128-col tile
    const int l31  = lane & 31;
    const int h    = lane >> 5;

    // XCD-chunked swizzle + 8x8 supertile (grid 8192 = 8 XCD x 1024).
    const int bid = blockIdx.x;
    const int nid = (bid & 7) * 1024 + (bid >> 3);
    const int sc  = nid >> 6, sl = nid & 63;
    const int by  = (sc & 7) * 8 + (sl >> 3);    // 0..63  (M/256)
    const int bx  = (sc >> 3) * 8 + (sl & 7);    // 0..127 (N/128)
    const size_t rowA0 = (size_t)by * 256;
    const size_t rowB0 = (size_t)bx * 128;

    const float b2 = bp[0] * L2E;

    // bias folded into MFMA C operand: acc ends as y = s' - b2
    f32x16 acc[2][2];
#pragma unroll
    for (int mf = 0; mf < 2; ++mf)
#pragma unroll
        for (int nf = 0; nf < 2; ++nf)
#pragma unroll
            for (int q = 0; q < 16; ++q) acc[mf][nf][q] = -b2;

    // LDS linear in chunk index; global SOURCE chunk pre-swizzled
    // ((c&7)^(row&7)) so read_frag's XOR'd ds_read_b128 is conflict-free.
#define STAGE(BUF, K0)                                                        \
    {                                                                         \
        _Pragma("unroll")                                                     \
        for (int p = 0; p < 4; ++p) {                                         \
            int c = p * 512 + tid; int row = c >> 3;                          \
            int scl = (c & 7) ^ (row & 7);                                    \
            gload_lds16(&ga[(rowA0 + row) * Dd + (K0) + scl * 16],            \
                        &As[BUF][c * 16]);                                    \
        }                                                                     \
        _Pragma("unroll")                                                     \
        for (int p = 0; p < 2; ++p) {                                         \
            int c = p * 512 + tid; int row = c >> 3;                          \
            int scl = (c & 7) ^ (row & 7);                                    \
            gload_lds16(&gb[(rowB0 + row) * Dd + (K0) + scl * 16],            \
                        &Bs[BUF][c * 16]);                                    \
        }                                                                     \
    }

#define COMPUTE(BUF)                                                          \
    {                                                                         \
        _Pragma("unroll")                                                     \
        for (int s = 0; s < 2; ++s) {                                         \
            int cb = s * 4 + h * 2;                                           \
            int8v aF0 = read_frag(As[BUF], wm * 64 + l31, cb);                \
            int8v aF1 = read_frag(As[BUF], wm * 64 + 32 + l31, cb);           \
            int8v bF0 = read_frag(Bs[BUF], wn * 64 + l31, cb);                \
            int8v bF1 = read_frag(Bs[BUF], wn * 64 + 32 + l31, cb);           \
            acc[0][0] = __builtin_amdgcn_mfma_scale_f32_32x32x64_f8f6f4(      \
                aF0, bF0, acc[0][0], 0, 0, 0, 0x7F7F7F7F, 0, 0x7F7F7F7F);     \
            acc[0][1] = __builtin_amdgcn_mfma_scale_f32_32x32x64_f8f6f4(      \
                aF0, bF1, acc[0][1], 0, 0, 0, 0x7F7F7F7F, 0, 0x7F7F7F7F);     \
            acc[1][0] = __builtin_amdgcn_mfma_scale_f32_32x32x64_f8f6f4(      \
                aF1, bF0, acc[1][0], 0, 0, 0, 0x7F7F7F7F, 0, 0x7F7F7F7F);     \
            acc[1][1] = __builtin_amdgcn_mfma_scale_f32_32x32x64_f8f6f4(      \
                aF1, bF1, acc[1][1], 0, 0, 0, 0x7F7F7F7F, 0, 0x7F7F7F7F);     \
        }                                                                     \
    }

    // ---- K = 256: two BK=128 tiles, double-buffered, counted vmcnt ----
    STAGE(0, 0)
    STAGE(1, 128)
    asm volatile("s_waitcnt vmcnt(6)" ::: "memory");   // tile0's 6 loads landed
    __builtin_amdgcn_s_barrier();
    COMPUTE(0)
    asm volatile("s_waitcnt vmcnt(0)" ::: "memory");   // tile1 landed
    __builtin_amdgcn_s_barrier();
    COMPUTE(1)
    // no trailing barrier: waves desync into the VALU/trans epilogue.

    // ---- epilogue ----
    // nats/elem = ln2*max(y,0) + ln(1+2^-|y|);  ln(1+e) ~= e - e^2/2
    // (mean bias ~ +0.003 over y~N(0,23) — far inside the 0.128 budget).
    float r1 = 0.f, r2 = 0.f, r2b = 0.f, ld = 0.f;
#pragma unroll
    for (int mf = 0; mf < 2; ++mf)
#pragma unroll
        for (int nf = 0; nf < 2; ++nf)
#pragma unroll
            for (int q = 0; q < 16; ++q) {
                float y = acc[mf][nf][q];
                r1 += fmaxf(y, 0.f);
                float e = __builtin_amdgcn_exp2f(-fabsf(y));
                r2 += e;
                r2b = fmaf(e, e, r2b);
            }

    // Diagonal correction where this block's row-range meets its col-range.
    if ((bx >> 1) == by) {
#pragma unroll
        for (int mf = 0; mf < 2; ++mf)
#pragma unroll
            for (int nf = 0; nf < 2; ++nf)
#pragma unroll
                for (int q = 0; q < 16; ++q) {
                    int i_loc = wm * 64 + mf * 32 + (q & 3) + 8 * (q >> 2) + 4 * h;
                    int j_loc = (bx & 1) * 128 + wn * 64 + nf * 32 + l31;
                    if (i_loc == j_loc) {
                        float y  = acc[mf][nf][q];
                        float u  = -(y + 2.f * b2);
                        float ey = __builtin_amdgcn_exp2f(-fabsf(y));
                        float eu = __builtin_amdgcn_exp2f(-fabsf(u));
                        float off = LN2 * fmaxf(y, 0.f) + ey - 0.5f * ey * ey;
                        float dg  = LN2 * fmaxf(u, 0.f) + eu - 0.5f * eu * eu;
                        ld += dg - off;
                    }
                }
    }

    float v = fmaf(LN2, r1, r2) - 0.5f * r2b + ld;   // nats

    // wave reduce then block reduce
#pragma unroll
    for (int off = 32; off; off >>= 1)
        v += __shfl_down(v, off);
    if (lane == 0) wsum[wid] = v;
    __syncthreads();
    if (tid == 0) {
        float t = 0.f;
#pragma unroll
        for (int w = 0; w < 8; ++w) t += wsum[w];
        atomicAdd(out, t * (1.0f / ((float)Nn * (float)Nn)));
    }
#undef STAGE
#undef COMPUTE
}

extern "C" void kernel_launch(void* const* d_in, const int* in_sizes, int n_in,
                              void* d_out, int out_size, void* d_ws, size_t ws_size,
                              hipStream_t stream) {
    const float* za   = (const float*)d_in[0];
    const float* zb   = (const float*)d_in[1];
    const float* bias = (const float*)d_in[2];

    unsigned char* wa = (unsigned char*)d_ws;
    unsigned char* wb = wa + (size_t)Nn * Dd;

    // zero the output accumulator (harness does not re-poison between replays)
    hipMemsetAsync(d_out, 0, sizeof(float), stream);

    // fp32 -> fp8 pre-pass (A pre-scaled by log2e)
    cvt_kernel<<<dim3(Nn * Dd / 2048), 256, 0, stream>>>(
        (const float4*)za, (const float4*)zb, (int2*)wa, (int2*)wb);

    // fused GEMM + loss: grid 64 x 128 = 8192 blocks
    siglip_kernel<<<dim3(8192), 512, 0, stream>>>(wa, wb, bias, (float*)d_out);
}